// Round 2
// baseline (528.820 us; speedup 1.0000x reference)
//
#include <hip/hip_runtime.h>
#include <hip/hip_bf16.h>

typedef unsigned short u16;
typedef unsigned int   u32;

#define D_ 128
#define B_ 2
#define F_ 256
#define T_ 256
#define FT (F_*T_)
#define XS 136     // ushort stride of x tiles

typedef __bf16 bf16x8 __attribute__((ext_vector_type(8)));
typedef float  floatx16 __attribute__((ext_vector_type(16)));

__device__ __forceinline__ u16 f2bf(float f) {
    union { __hip_bfloat16 h; u16 u; } cv; cv.h = __float2bfloat16(f); return cv.u;
}
__device__ __forceinline__ u32 pk2(float lo, float hi2) {
    union { __hip_bfloat162 h; u32 u; } cv;
    cv.h = __float22bfloat162_rn(make_float2(lo, hi2)); return cv.u;
}
__device__ __forceinline__ float bf2f(u16 u) { return __uint_as_float(((u32)u) << 16); }

// ---------------------------------------------------------------------------
// Precompute effective fused weights (unchanged).
// ---------------------------------------------------------------------------
__global__ __launch_bounds__(128) void precompute_eff(
    const float* __restrict__ lnqg, const float* __restrict__ lnqb,
    const float* __restrict__ lnkg, const float* __restrict__ lnkb,
    const float* __restrict__ Wq, const float* __restrict__ bq,
    const float* __restrict__ Wk, const float* __restrict__ bk,
    const float* __restrict__ Wv, const float* __restrict__ bv,
    const float* __restrict__ in_w, const float* __restrict__ in_b,
    const float* __restrict__ ow,
    u16* __restrict__ Agb, u16* __restrict__ Ob,
    float* __restrict__ sA, float* __restrict__ cb)
{
    const int j = blockIdx.x;
    const int sel = blockIdx.y;    // 0=q,1=k,2=v,3=out_w convert
    const int i = threadIdx.x;
    if (sel == 3) { Ob[j*D_ + i] = f2bf(ow[j*D_ + i]); return; }

    const float* W  = (sel==0) ? Wq : (sel==1) ? Wk : Wv;
    const float* bW = (sel==0) ? bq : (sel==1) ? bk : bv;
    const float* g  = (sel==0) ? lnqg : lnkg;
    const float* bl = (sel==0) ? lnqb : lnkb;

    __shared__ float row[D_];
    __shared__ float red[D_];
    row[i] = in_w[(sel*D_ + j)*D_ + i];
    __syncthreads();
    float acc = 0.f;
    #pragma unroll 8
    for (int m = 0; m < D_; ++m) acc = fmaf(row[m], W[m*D_ + i], acc);
    float ag = acc * g[i];
    Agb[sel*D_*D_ + j*D_ + i] = f2bf(ag);

    red[i] = ag;
    __syncthreads();
    for (int s = 64; s > 0; s >>= 1) { if (i < s) red[i] += red[i+s]; __syncthreads(); }
    if (i == 0) sA[sel*D_ + j] = red[0];
    __syncthreads();
    red[i] = acc * bl[i] + row[i] * bW[i];
    __syncthreads();
    for (int s = 64; s > 0; s >>= 1) { if (i < s) red[i] += red[i+s]; __syncthreads(); }
    if (i == 0) cb[sel*D_ + j] = red[0] + in_b[sel*D_ + j];
}

// ---------------------------------------------------------------------------
// Main fused kernel. Block = 32 tokens of one (b,f). 4 waves, wave = head.
//
// Round-2 restructure: q/k/v gemms use SWAPPED operand order
// mfma(W_frag, x_frag) so C comes out col=token, rows=dims. Each lane then
// holds 16 of its token's 32 head-dims -> scores are an in-register dot
// (16 FMA + shfl_xor(32)), softmax is fully in-register, V-weights are
// per-lane scalars. Deletes the whole stage/readback/diag LDS path and the
// qk/swt buffers: LDS 48KB -> 35.5KB -> 4 blocks/CU.
// ---------------------------------------------------------------------------
__global__ __launch_bounds__(256, 4) void cca_mfma(
    const float* __restrict__ h,      // (C,B,128,F,T) fp32
    const u16*  __restrict__ Agb,     // 3 x [128][128] bf16 (q,k,v fused)
    const u16*  __restrict__ Ob,      // [128][128] bf16 out_w
    const float* __restrict__ sA,     // 3x128
    const float* __restrict__ cbp,    // 3x128
    const float* __restrict__ out_b,  // 128
    float* __restrict__ outp)         // (B,128,F,T)
{
    __shared__ __align__(16) u16 xb[4][32*XS];    // 34816 B, r-scaled bf16 x
    __shared__ float rmneg[4][32];                // 512 B   -r*m per (c,t)
    __shared__ float invr[32];                    // 128 B   1/r for c=0

    const int tid = threadIdx.x;
    const int blk = blockIdx.x;                  // 4096 = 2*256*8
    const int t0 = (blk & 7) * 32;
    const int f  = (blk >> 3) & 255;
    const int b  = blk >> 11;

    // ---------------- load all 4 context tiles (fp32 -> bf16 packed) -------
    {
        const int dd = tid >> 3;          // d-pair index 0..31
        const int t4 = (tid & 7) * 4;
        #pragma unroll
        for (int it = 0; it < 2; ++it) {
            const int d = 2*dd + 64*it;
            #pragma unroll
            for (int c = 0; c < 4; ++c) {
                const float* p = h + ((size_t)((c*B_ + b)*D_ + d))*FT + (size_t)f*T_ + t0 + t4;
                float4 v0 = *(const float4*)p;
                float4 v1 = *(const float4*)(p + FT);
                u32* dst = (u32*)xb[c] + dd + 32*it;
                dst[(size_t)(t4+0)*(XS/2)] = pk2(v0.x, v1.x);
                dst[(size_t)(t4+1)*(XS/2)] = pk2(v0.y, v1.y);
                dst[(size_t)(t4+2)*(XS/2)] = pk2(v0.z, v1.z);
                dst[(size_t)(t4+3)*(XS/2)] = pk2(v0.w, v1.w);
            }
        }
    }
    __syncthreads();

    // ---------- stats + in-place r-scale (thread = half-row of (c,t)) ------
    {
        const int rowi = tid >> 1, half = tid & 1;
        const int c = rowi >> 5, t = rowi & 31;
        u32* rowp = (u32*)(xb[c] + t*XS) + half*32;
        u32 rw[32];
        #pragma unroll
        for (int i = 0; i < 8; ++i) {
            uint4 q = ((const uint4*)rowp)[i];
            rw[4*i] = q.x; rw[4*i+1] = q.y; rw[4*i+2] = q.z; rw[4*i+3] = q.w;
        }
        float s = 0.f, sq = 0.f;
        #pragma unroll
        for (int k = 0; k < 32; ++k) {
            float lo = __uint_as_float(rw[k] << 16);
            float hi2 = __uint_as_float(rw[k] & 0xffff0000u);
            s += lo + hi2;
            sq = fmaf(lo, lo, fmaf(hi2, hi2, sq));
        }
        s += __shfl_xor(s, 1);
        sq += __shfl_xor(sq, 1);
        float m = s * (1.f/128.f);
        float var = fmaf(-m, m, sq * (1.f/128.f));
        float r = rsqrtf(var + 1e-5f);
        #pragma unroll
        for (int i = 0; i < 8; ++i) {
            uint4 q;
            q.x = pk2(__uint_as_float(rw[4*i]   << 16)*r, __uint_as_float(rw[4*i]   & 0xffff0000u)*r);
            q.y = pk2(__uint_as_float(rw[4*i+1] << 16)*r, __uint_as_float(rw[4*i+1] & 0xffff0000u)*r);
            q.z = pk2(__uint_as_float(rw[4*i+2] << 16)*r, __uint_as_float(rw[4*i+2] & 0xffff0000u)*r);
            q.w = pk2(__uint_as_float(rw[4*i+3] << 16)*r, __uint_as_float(rw[4*i+3] & 0xffff0000u)*r);
            ((uint4*)rowp)[i] = q;
        }
        if (half == 0) {
            rmneg[c][t] = -r*m;
            if (c == 0) invr[t] = 1.0f / r;
        }
    }
    __syncthreads();

    // ---------------- per-wave setup (wave = head) -------------------------
    const int wv  = tid >> 6;
    const int l   = tid & 63;
    const int lo5 = l & 31, hi = l >> 5;
    const int jq  = wv*32 + lo5;
    const int xoff = lo5*XS + hi*8;

    const u16* Bq = Agb +         (size_t)jq*D_ + hi*8;
    const u16* Bk = Agb + 16384 + (size_t)jq*D_ + hi*8;
    const u16* Bv = Agb + 32768 + (size_t)jq*D_ + hi*8;
    const u16* Bo = Ob  +         (size_t)jq*D_ + hi*8;

    // per-reg fold vectors: sA/cb at dims j = wv*32 + 8g + 4hi + e
    auto ldvec = [&](const float* base) -> floatx16 {
        floatx16 r;
        #pragma unroll
        for (int g = 0; g < 4; ++g) {
            float4 v = *(const float4*)(base + wv*32 + 8*g + 4*hi);
            r[4*g+0]=v.x; r[4*g+1]=v.y; r[4*g+2]=v.z; r[4*g+3]=v.w;
        }
        return r;
    };

    // ---------------- q gemm (swapped): lane holds Q[token lo5][16 dims] ---
    floatx16 qa;
    #pragma unroll
    for (int i = 0; i < 16; ++i) qa[i] = 0.f;
    __builtin_amdgcn_s_setprio(1);
    #pragma unroll
    for (int ks = 0; ks < 8; ++ks) {
        bf16x8 w = *(const bf16x8*)(Bq + ks*16);
        bf16x8 a = *(const bf16x8*)(xb[0] + xoff + ks*16);
        qa = __builtin_amdgcn_mfma_f32_32x32x16_bf16(w, a, qa, 0, 0, 0);
    }
    __builtin_amdgcn_s_setprio(0);
    {
        floatx16 sAq_ = ldvec(sA);
        floatx16 cbq_ = ldvec(cbp);
        const float rm = rmneg[0][lo5];
        #pragma unroll
        for (int i = 0; i < 16; ++i) qa[i] += fmaf(rm, sAq_[i], cbq_[i]);
    }

    // ---------------- k phase: 2x2 accs, in-register score dot -------------
    float sreg[4];
    {
        floatx16 sAk_ = ldvec(sA + 128);
        floatx16 cbk_ = ldvec(cbp + 128);
        #pragma unroll
        for (int cp = 0; cp < 4; cp += 2) {
            floatx16 k0, k1;
            #pragma unroll
            for (int i = 0; i < 16; ++i) { k0[i]=0.f; k1[i]=0.f; }
            __builtin_amdgcn_s_setprio(1);
            #pragma unroll
            for (int ks = 0; ks < 8; ++ks) {
                bf16x8 w  = *(const bf16x8*)(Bk + ks*16);
                bf16x8 a0 = *(const bf16x8*)(xb[cp]   + xoff + ks*16);
                bf16x8 a1 = *(const bf16x8*)(xb[cp+1] + xoff + ks*16);
                k0 = __builtin_amdgcn_mfma_f32_32x32x16_bf16(w, a0, k0, 0, 0, 0);
                k1 = __builtin_amdgcn_mfma_f32_32x32x16_bf16(w, a1, k1, 0, 0, 0);
            }
            __builtin_amdgcn_s_setprio(0);
            const float rm0 = rmneg[cp][lo5], rm1 = rmneg[cp+1][lo5];
            float p0 = 0.f, p1 = 0.f;
            #pragma unroll
            for (int i = 0; i < 16; ++i) {
                p0 = fmaf(qa[i], k0[i] + fmaf(rm0, sAk_[i], cbk_[i]), p0);
                p1 = fmaf(qa[i], k1[i] + fmaf(rm1, sAk_[i], cbk_[i]), p1);
            }
            p0 += __shfl_xor(p0, 32);
            p1 += __shfl_xor(p1, 32);
            sreg[cp]   = p0 * 0.17677669529663687f;   // 1/sqrt(32)
            sreg[cp+1] = p1 * 0.17677669529663687f;
        }
    }

    // ---------------- softmax fully in-register (all lanes) ----------------
    float w0, w1, w2, w3;
    {
        float mm = fmaxf(fmaxf(sreg[0], sreg[1]), fmaxf(sreg[2], sreg[3]));
        float e0 = __expf(sreg[0]-mm), e1 = __expf(sreg[1]-mm);
        float e2 = __expf(sreg[2]-mm), e3 = __expf(sreg[3]-mm);
        float inv = 1.f / (e0+e1+e2+e3);
        w0 = e0*inv; w1 = e1*inv; w2 = e2*inv; w3 = e3*inv;
    }

    // ---------------- v phase: 2x2 accs, scalar-weighted into ctx ----------
    floatx16 ctx;
    #pragma unroll
    for (int i = 0; i < 16; ++i) ctx[i] = 0.f;
    {
        floatx16 sAv_ = ldvec(sA + 256);
        floatx16 cbv_ = ldvec(cbp + 256);
        #pragma unroll
        for (int cp = 0; cp < 4; cp += 2) {
            floatx16 va0, va1;
            #pragma unroll
            for (int i = 0; i < 16; ++i) { va0[i]=0.f; va1[i]=0.f; }
            __builtin_amdgcn_s_setprio(1);
            #pragma unroll
            for (int ks = 0; ks < 8; ++ks) {
                bf16x8 w  = *(const bf16x8*)(Bv + ks*16);
                bf16x8 a0 = *(const bf16x8*)(xb[cp]   + xoff + ks*16);
                bf16x8 a1 = *(const bf16x8*)(xb[cp+1] + xoff + ks*16);
                va0 = __builtin_amdgcn_mfma_f32_32x32x16_bf16(w, a0, va0, 0, 0, 0);
                va1 = __builtin_amdgcn_mfma_f32_32x32x16_bf16(w, a1, va1, 0, 0, 0);
            }
            __builtin_amdgcn_s_setprio(0);
            #pragma unroll
            for (int d = 0; d < 2; ++d) {
                const int c = cp + d;
                floatx16& va = d ? va1 : va0;
                const float rm  = rmneg[c][lo5];
                const float wgt = (c==0) ? w0 : (c==1) ? w1 : (c==2) ? w2 : w3;
                #pragma unroll
                for (int i = 0; i < 16; ++i)
                    ctx[i] = fmaf(wgt, va[i] + fmaf(rm, sAv_[i], cbv_[i]), ctx[i]);
            }
        }
    }

    // ---------------- ctx -> xb[1] (bf16), out-proj, residual, store -------
    __syncthreads();                       // all waves done reading x tiles
    #pragma unroll
    for (int g = 0; g < 4; ++g) {
        // dims j = wv*32 + 8g + 4hi + {0..3} for token lo5
        uint2 wr;
        wr.x = pk2(ctx[4*g+0], ctx[4*g+1]);
        wr.y = pk2(ctx[4*g+2], ctx[4*g+3]);
        *(uint2*)(xb[1] + lo5*XS + wv*32 + 8*g + 4*hi) = wr;
    }
    __syncthreads();                       // ctx visible to all waves

    floatx16 oa;
    #pragma unroll
    for (int i = 0; i < 16; ++i) oa[i] = 0.f;
    __builtin_amdgcn_s_setprio(1);
    #pragma unroll
    for (int ks = 0; ks < 8; ++ks) {
        bf16x8 a  = *(const bf16x8*)(xb[1] + xoff + ks*16);
        bf16x8 bb = *(const bf16x8*)(Bo + ks*16);
        oa = __builtin_amdgcn_mfma_f32_32x32x16_bf16(a, bb, oa, 0, 0, 0);
    }
    __builtin_amdgcn_s_setprio(0);
    const float obv = out_b[jq];
    float* obase = outp + ((size_t)(b*D_ + jq))*FT + (size_t)f*T_ + t0;
    #pragma unroll
    for (int g = 0; g < 4; ++g) {
        const int tb = 8*g + 4*hi;
        float4 iv4 = *(const float4*)&invr[tb];
        float4 st;
        st.x = oa[g*4+0] + obv + bf2f(xb[0][(tb+0)*XS + jq]) * iv4.x;
        st.y = oa[g*4+1] + obv + bf2f(xb[0][(tb+1)*XS + jq]) * iv4.y;
        st.z = oa[g*4+2] + obv + bf2f(xb[0][(tb+2)*XS + jq]) * iv4.z;
        st.w = oa[g*4+3] + obv + bf2f(xb[0][(tb+3)*XS + jq]) * iv4.w;
        *(float4*)(obase + tb) = st;
    }
}

extern "C" void kernel_launch(void* const* d_in, const int* in_sizes, int n_in,
                              void* d_out, int out_size, void* d_ws, size_t ws_size,
                              hipStream_t stream) {
    const float* h    = (const float*)d_in[0];
    const float* lnqg = (const float*)d_in[1];
    const float* lnqb = (const float*)d_in[2];
    const float* lnkg = (const float*)d_in[3];
    const float* lnkb = (const float*)d_in[4];
    const float* Wq   = (const float*)d_in[5];
    const float* bq   = (const float*)d_in[6];
    const float* Wk   = (const float*)d_in[7];
    const float* bk   = (const float*)d_in[8];
    const float* Wv   = (const float*)d_in[9];
    const float* bv   = (const float*)d_in[10];
    const float* in_w = (const float*)d_in[11];
    const float* in_b = (const float*)d_in[12];
    const float* ow   = (const float*)d_in[13];
    const float* ob   = (const float*)d_in[14];

    char* ws = (char*)d_ws;
    u16*   Agb = (u16*)ws;                          // 3*16384 u16 = 98304 B
    u16*   Obf = (u16*)(ws + 98304);                // 16384 u16  = 32768 B
    float* sAe = (float*)(ws + 98304 + 32768);      // 384 f
    float* cbe = (float*)(ws + 98304 + 32768 + 1536);

    precompute_eff<<<dim3(128, 4), 128, 0, stream>>>(
        lnqg, lnqb, lnkg, lnkb, Wq, bq, Wk, bk, Wv, bv,
        in_w, in_b, ow, Agb, Obf, sAe, cbe);
    cca_mfma<<<dim3(B_*F_*(T_/32)), 256, 0, stream>>>(
        h, Agb, Obf, sAe, cbe, ob, (float*)d_out);
}

// Round 17
// 494.151 us; speedup vs baseline: 1.0702x; 1.0702x over previous
//
#include <hip/hip_runtime.h>
#include <hip/hip_bf16.h>

typedef unsigned short u16;
typedef unsigned int   u32;

#define D_ 128
#define B_ 2
#define F_ 256
#define T_ 256
#define FT (F_*T_)
#define XS 136     // ushort stride of x tiles

typedef __bf16 bf16x8 __attribute__((ext_vector_type(8)));
typedef float  floatx16 __attribute__((ext_vector_type(16)));

__device__ __forceinline__ u16 f2bf(float f) {
    union { __hip_bfloat16 h; u16 u; } cv; cv.h = __float2bfloat16(f); return cv.u;
}
__device__ __forceinline__ u32 pk2(float lo, float hi2) {
    union { __hip_bfloat162 h; u32 u; } cv;
    cv.h = __float22bfloat162_rn(make_float2(lo, hi2)); return cv.u;
}
__device__ __forceinline__ float bf2f(u16 u) { return __uint_as_float(((u32)u) << 16); }

// ---------------------------------------------------------------------------
// Precompute effective fused weights (unchanged).
// ---------------------------------------------------------------------------
__global__ __launch_bounds__(128) void precompute_eff(
    const float* __restrict__ lnqg, const float* __restrict__ lnqb,
    const float* __restrict__ lnkg, const float* __restrict__ lnkb,
    const float* __restrict__ Wq, const float* __restrict__ bq,
    const float* __restrict__ Wk, const float* __restrict__ bk,
    const float* __restrict__ Wv, const float* __restrict__ bv,
    const float* __restrict__ in_w, const float* __restrict__ in_b,
    const float* __restrict__ ow,
    u16* __restrict__ Agb, u16* __restrict__ Ob,
    float* __restrict__ sA, float* __restrict__ cb)
{
    const int j = blockIdx.x;
    const int sel = blockIdx.y;    // 0=q,1=k,2=v,3=out_w convert
    const int i = threadIdx.x;
    if (sel == 3) { Ob[j*D_ + i] = f2bf(ow[j*D_ + i]); return; }

    const float* W  = (sel==0) ? Wq : (sel==1) ? Wk : Wv;
    const float* bW = (sel==0) ? bq : (sel==1) ? bk : bv;
    const float* g  = (sel==0) ? lnqg : lnkg;
    const float* bl = (sel==0) ? lnqb : lnkb;

    __shared__ float row[D_];
    __shared__ float red[D_];
    row[i] = in_w[(sel*D_ + j)*D_ + i];
    __syncthreads();
    float acc = 0.f;
    #pragma unroll 8
    for (int m = 0; m < D_; ++m) acc = fmaf(row[m], W[m*D_ + i], acc);
    float ag = acc * g[i];
    Agb[sel*D_*D_ + j*D_ + i] = f2bf(ag);

    red[i] = ag;
    __syncthreads();
    for (int s = 64; s > 0; s >>= 1) { if (i < s) red[i] += red[i+s]; __syncthreads(); }
    if (i == 0) sA[sel*D_ + j] = red[0];
    __syncthreads();
    red[i] = acc * bl[i] + row[i] * bW[i];
    __syncthreads();
    for (int s = 64; s > 0; s >>= 1) { if (i < s) red[i] += red[i+s]; __syncthreads(); }
    if (i == 0) cb[sel*D_ + j] = red[0] + in_b[sel*D_ + j];
}

// ---------------------------------------------------------------------------
// Main fused kernel. Block = 32 tokens of one (b,f). 4 waves, wave = head.
//
// Round-3 (14th resubmit after infra timeouts): swapped-MFMA structure
// (scores in-register, softmax in-register) with the affine-correction
// folds FACTORED to kill long-lived registers (round 2 spilled:
// WRITE_SIZE 180MB vs 66MB ideal, VGPR squeezed to 64):
//  - k fold: p_c = dot(qa,k_c) + rm_c*dqs + dqc, dqs/dqc computed once.
//  - v fold: sum_c w_c = 1  =>  ctx += (sum_c w_c*rm_c)*sAv + cbv, once.
// Peak live regs ~90 < 128 budget @ 4 blocks/CU -> no scratch.
// ---------------------------------------------------------------------------
__global__ __launch_bounds__(256, 4) void cca_mfma(
    const float* __restrict__ h,      // (C,B,128,F,T) fp32
    const u16*  __restrict__ Agb,     // 3 x [128][128] bf16 (q,k,v fused)
    const u16*  __restrict__ Ob,      // [128][128] bf16 out_w
    const float* __restrict__ sA,     // 3x128
    const float* __restrict__ cbp,    // 3x128
    const float* __restrict__ out_b,  // 128
    float* __restrict__ outp)         // (B,128,F,T)
{
    __shared__ __align__(16) u16 xb[4][32*XS];    // 34816 B, r-scaled bf16 x
    __shared__ float rmneg[4][32];                // 512 B   -r*m per (c,t)
    __shared__ float invr[32];                    // 128 B   1/r for c=0

    const int tid = threadIdx.x;
    const int blk = blockIdx.x;                  // 4096 = 2*256*8
    const int t0 = (blk & 7) * 32;
    const int f  = (blk >> 3) & 255;
    const int b  = blk >> 11;

    // ---------------- load all 4 context tiles (fp32 -> bf16 packed) -------
    {
        const int dd = tid >> 3;          // d-pair index 0..31
        const int t4 = (tid & 7) * 4;
        #pragma unroll
        for (int it = 0; it < 2; ++it) {
            const int d = 2*dd + 64*it;
            #pragma unroll
            for (int c = 0; c < 4; ++c) {
                const float* p = h + ((size_t)((c*B_ + b)*D_ + d))*FT + (size_t)f*T_ + t0 + t4;
                float4 v0 = *(const float4*)p;
                float4 v1 = *(const float4*)(p + FT);
                u32* dst = (u32*)xb[c] + dd + 32*it;
                dst[(size_t)(t4+0)*(XS/2)] = pk2(v0.x, v1.x);
                dst[(size_t)(t4+1)*(XS/2)] = pk2(v0.y, v1.y);
                dst[(size_t)(t4+2)*(XS/2)] = pk2(v0.z, v1.z);
                dst[(size_t)(t4+3)*(XS/2)] = pk2(v0.w, v1.w);
            }
        }
    }
    __syncthreads();

    // ---------- stats + in-place r-scale (thread = half-row of (c,t)) ------
    {
        const int rowi = tid >> 1, half = tid & 1;
        const int c = rowi >> 5, t = rowi & 31;
        u32* rowp = (u32*)(xb[c] + t*XS) + half*32;
        u32 rw[32];
        #pragma unroll
        for (int i = 0; i < 8; ++i) {
            uint4 q = ((const uint4*)rowp)[i];
            rw[4*i] = q.x; rw[4*i+1] = q.y; rw[4*i+2] = q.z; rw[4*i+3] = q.w;
        }
        float s = 0.f, sq = 0.f;
        #pragma unroll
        for (int k = 0; k < 32; ++k) {
            float lo = __uint_as_float(rw[k] << 16);
            float hi2 = __uint_as_float(rw[k] & 0xffff0000u);
            s += lo + hi2;
            sq = fmaf(lo, lo, fmaf(hi2, hi2, sq));
        }
        s += __shfl_xor(s, 1);
        sq += __shfl_xor(sq, 1);
        float m = s * (1.f/128.f);
        float var = fmaf(-m, m, sq * (1.f/128.f));
        float r = rsqrtf(var + 1e-5f);
        #pragma unroll
        for (int i = 0; i < 8; ++i) {
            uint4 q;
            q.x = pk2(__uint_as_float(rw[4*i]   << 16)*r, __uint_as_float(rw[4*i]   & 0xffff0000u)*r);
            q.y = pk2(__uint_as_float(rw[4*i+1] << 16)*r, __uint_as_float(rw[4*i+1] & 0xffff0000u)*r);
            q.z = pk2(__uint_as_float(rw[4*i+2] << 16)*r, __uint_as_float(rw[4*i+2] & 0xffff0000u)*r);
            q.w = pk2(__uint_as_float(rw[4*i+3] << 16)*r, __uint_as_float(rw[4*i+3] & 0xffff0000u)*r);
            ((uint4*)rowp)[i] = q;
        }
        if (half == 0) {
            rmneg[c][t] = -r*m;
            if (c == 0) invr[t] = 1.0f / r;
        }
    }
    __syncthreads();

    // ---------------- per-wave setup (wave = head) -------------------------
    const int wv  = tid >> 6;
    const int l   = tid & 63;
    const int lo5 = l & 31, hi = l >> 5;
    const int jq  = wv*32 + lo5;
    const int xoff = lo5*XS + hi*8;

    const u16* Bq = Agb +         (size_t)jq*D_ + hi*8;
    const u16* Bk = Agb + 16384 + (size_t)jq*D_ + hi*8;
    const u16* Bv = Agb + 32768 + (size_t)jq*D_ + hi*8;
    const u16* Bo = Ob  +         (size_t)jq*D_ + hi*8;

    // ---------------- q gemm (swapped): lane holds Q[token lo5][16 dims] ---
    floatx16 qa;
    #pragma unroll
    for (int i = 0; i < 16; ++i) qa[i] = 0.f;
    __builtin_amdgcn_s_setprio(1);
    #pragma unroll
    for (int ks = 0; ks < 8; ++ks) {
        bf16x8 w = *(const bf16x8*)(Bq + ks*16);
        bf16x8 a = *(const bf16x8*)(xb[0] + xoff + ks*16);
        qa = __builtin_amdgcn_mfma_f32_32x32x16_bf16(w, a, qa, 0, 0, 0);
    }
    __builtin_amdgcn_s_setprio(0);
    // q fold: load, use, die (no long-lived vectors)
    {
        const float rm = rmneg[0][lo5];
        #pragma unroll
        for (int g = 0; g < 4; ++g) {
            float4 sv = *(const float4*)(sA  + wv*32 + 8*g + 4*hi);
            float4 cv = *(const float4*)(cbp + wv*32 + 8*g + 4*hi);
            qa[4*g+0] += fmaf(rm, sv.x, cv.x);
            qa[4*g+1] += fmaf(rm, sv.y, cv.y);
            qa[4*g+2] += fmaf(rm, sv.z, cv.z);
            qa[4*g+3] += fmaf(rm, sv.w, cv.w);
        }
    }

    // ---- k-correction dots: dqs = qa.sAk, dqc = qa.cbk (computed once) ----
    float dqs = 0.f, dqc = 0.f;
    #pragma unroll
    for (int g = 0; g < 4; ++g) {
        float4 sv = *(const float4*)(sA  + 128 + wv*32 + 8*g + 4*hi);
        float4 cv = *(const float4*)(cbp + 128 + wv*32 + 8*g + 4*hi);
        dqs = fmaf(qa[4*g+0], sv.x, dqs); dqc = fmaf(qa[4*g+0], cv.x, dqc);
        dqs = fmaf(qa[4*g+1], sv.y, dqs); dqc = fmaf(qa[4*g+1], cv.y, dqc);
        dqs = fmaf(qa[4*g+2], sv.z, dqs); dqc = fmaf(qa[4*g+2], cv.z, dqc);
        dqs = fmaf(qa[4*g+3], sv.w, dqs); dqc = fmaf(qa[4*g+3], cv.w, dqc);
    }

    // ---------------- k phase: 2x2 accs, in-register score dot -------------
    float sreg[4];
    #pragma unroll
    for (int cp = 0; cp < 4; cp += 2) {
        floatx16 k0, k1;
        #pragma unroll
        for (int i = 0; i < 16; ++i) { k0[i]=0.f; k1[i]=0.f; }
        __builtin_amdgcn_s_setprio(1);
        #pragma unroll
        for (int ks = 0; ks < 8; ++ks) {
            bf16x8 w  = *(const bf16x8*)(Bk + ks*16);
            bf16x8 a0 = *(const bf16x8*)(xb[cp]   + xoff + ks*16);
            bf16x8 a1 = *(const bf16x8*)(xb[cp+1] + xoff + ks*16);
            k0 = __builtin_amdgcn_mfma_f32_32x32x16_bf16(w, a0, k0, 0, 0, 0);
            k1 = __builtin_amdgcn_mfma_f32_32x32x16_bf16(w, a1, k1, 0, 0, 0);
        }
        __builtin_amdgcn_s_setprio(0);
        const float rm0 = rmneg[cp][lo5], rm1 = rmneg[cp+1][lo5];
        float p0 = fmaf(rm0, dqs, dqc);
        float p1 = fmaf(rm1, dqs, dqc);
        #pragma unroll
        for (int i = 0; i < 16; ++i) {
            p0 = fmaf(qa[i], k0[i], p0);
            p1 = fmaf(qa[i], k1[i], p1);
        }
        p0 += __shfl_xor(p0, 32);
        p1 += __shfl_xor(p1, 32);
        sreg[cp]   = p0 * 0.17677669529663687f;   // 1/sqrt(32)
        sreg[cp+1] = p1 * 0.17677669529663687f;
    }

    // ---------------- softmax fully in-register (all lanes) ----------------
    float w0, w1, w2, w3;
    {
        float mm = fmaxf(fmaxf(sreg[0], sreg[1]), fmaxf(sreg[2], sreg[3]));
        float e0 = __expf(sreg[0]-mm), e1 = __expf(sreg[1]-mm);
        float e2 = __expf(sreg[2]-mm), e3 = __expf(sreg[3]-mm);
        float inv = 1.f / (e0+e1+e2+e3);
        w0 = e0*inv; w1 = e1*inv; w2 = e2*inv; w3 = e3*inv;
    }

    // ---------------- v phase: 2x2 accs, scalar-weighted into ctx ----------
    floatx16 ctx;
    #pragma unroll
    for (int i = 0; i < 16; ++i) ctx[i] = 0.f;
    #pragma unroll
    for (int cp = 0; cp < 4; cp += 2) {
        floatx16 va0, va1;
        #pragma unroll
        for (int i = 0; i < 16; ++i) { va0[i]=0.f; va1[i]=0.f; }
        __builtin_amdgcn_s_setprio(1);
        #pragma unroll
        for (int ks = 0; ks < 8; ++ks) {
            bf16x8 w  = *(const bf16x8*)(Bv + ks*16);
            bf16x8 a0 = *(const bf16x8*)(xb[cp]   + xoff + ks*16);
            bf16x8 a1 = *(const bf16x8*)(xb[cp+1] + xoff + ks*16);
            va0 = __builtin_amdgcn_mfma_f32_32x32x16_bf16(w, a0, va0, 0, 0, 0);
            va1 = __builtin_amdgcn_mfma_f32_32x32x16_bf16(w, a1, va1, 0, 0, 0);
        }
        __builtin_amdgcn_s_setprio(0);
        const float wa = (cp==0) ? w0 : w2;
        const float wb = (cp==0) ? w1 : w3;
        #pragma unroll
        for (int i = 0; i < 16; ++i)
            ctx[i] = fmaf(wa, va0[i], fmaf(wb, va1[i], ctx[i]));
    }
    // v fold applied ONCE (sum_c w_c == 1): ctx += (sum w_c*rm_c)*sAv + cbv
    {
        float wr = w0*rmneg[0][lo5] + w1*rmneg[1][lo5]
                 + w2*rmneg[2][lo5] + w3*rmneg[3][lo5];
        #pragma unroll
        for (int g = 0; g < 4; ++g) {
            float4 sv = *(const float4*)(sA  + 256 + wv*32 + 8*g + 4*hi);
            float4 cv = *(const float4*)(cbp + 256 + wv*32 + 8*g + 4*hi);
            ctx[4*g+0] += fmaf(wr, sv.x, cv.x);
            ctx[4*g+1] += fmaf(wr, sv.y, cv.y);
            ctx[4*g+2] += fmaf(wr, sv.z, cv.z);
            ctx[4*g+3] += fmaf(wr, sv.w, cv.w);
        }
    }

    // ---------------- ctx -> xb[1] (bf16), out-proj, residual, store -------
    __syncthreads();                       // all waves done reading x tiles
    #pragma unroll
    for (int g = 0; g < 4; ++g) {
        // dims j = wv*32 + 8g + 4hi + {0..3} for token lo5
        uint2 wr2;
        wr2.x = pk2(ctx[4*g+0], ctx[4*g+1]);
        wr2.y = pk2(ctx[4*g+2], ctx[4*g+3]);
        *(uint2*)(xb[1] + lo5*XS + wv*32 + 8*g + 4*hi) = wr2;
    }
    __syncthreads();                       // ctx visible to all waves

    floatx16 oa;
    #pragma unroll
    for (int i = 0; i < 16; ++i) oa[i] = 0.f;
    __builtin_amdgcn_s_setprio(1);
    #pragma unroll
    for (int ks = 0; ks < 8; ++ks) {
        bf16x8 a  = *(const bf16x8*)(xb[1] + xoff + ks*16);
        bf16x8 bb = *(const bf16x8*)(Bo + ks*16);
        oa = __builtin_amdgcn_mfma_f32_32x32x16_bf16(a, bb, oa, 0, 0, 0);
    }
    __builtin_amdgcn_s_setprio(0);
    const float obv = out_b[jq];
    float* obase = outp + ((size_t)(b*D_ + jq))*FT + (size_t)f*T_ + t0;
    #pragma unroll
    for (int g = 0; g < 4; ++g) {
        const int tb = 8*g + 4*hi;
        float4 iv4 = *(const float4*)&invr[tb];
        float4 st;
        st.x = oa[g*4+0] + obv + bf2f(xb[0][(tb+0)*XS + jq]) * iv4.x;
        st.y = oa[g*4+1] + obv + bf2f(xb[0][(tb+1)*XS + jq]) * iv4.y;
        st.z = oa[g*4+2] + obv + bf2f(xb[0][(tb+2)*XS + jq]) * iv4.z;
        st.w = oa[g*4+3] + obv + bf2f(xb[0][(tb+3)*XS + jq]) * iv4.w;
        *(float4*)(obase + tb) = st;
    }
}

extern "C" void kernel_launch(void* const* d_in, const int* in_sizes, int n_in,
                              void* d_out, int out_size, void* d_ws, size_t ws_size,
                              hipStream_t stream) {
    const float* h    = (const float*)d_in[0];
    const float* lnqg = (const float*)d_in[1];
    const float* lnqb = (const float*)d_in[2];
    const float* lnkg = (const float*)d_in[3];
    const float* lnkb = (const float*)d_in[4];
    const float* Wq   = (const float*)d_in[5];
    const float* bq   = (const float*)d_in[6];
    const float* Wk   = (const float*)d_in[7];
    const float* bk   = (const float*)d_in[8];
    const float* Wv   = (const float*)d_in[9];
    const float* bv   = (const float*)d_in[10];
    const float* in_w = (const float*)d_in[11];
    const float* in_b = (const float*)d_in[12];
    const float* ow   = (const float*)d_in[13];
    const float* ob   = (const float*)d_in[14];

    char* ws = (char*)d_ws;
    u16*   Agb = (u16*)ws;                          // 3*16384 u16 = 98304 B
    u16*   Obf = (u16*)(ws + 98304);                // 16384 u16  = 32768 B
    float* sAe = (float*)(ws + 98304 + 32768);      // 384 f
    float* cbe = (float*)(ws + 98304 + 32768 + 1536);

    precompute_eff<<<dim3(128, 4), 128, 0, stream>>>(
        lnqg, lnqb, lnkg, lnkb, Wq, bq, Wk, bk, Wv, bv,
        in_w, in_b, ow, Agb, Obf, sAe, cbe);
    cca_mfma<<<dim3(B_*F_*(T_/32)), 256, 0, stream>>>(
        h, Agb, Obf, sAe, cbe, ob, (float*)d_out);
}

// Round 20
// 484.821 us; speedup vs baseline: 1.0908x; 1.0192x over previous
//
#include <hip/hip_runtime.h>
#include <hip/hip_bf16.h>

typedef unsigned short u16;
typedef unsigned int   u32;

#define D_ 128
#define B_ 2
#define F_ 256
#define T_ 256
#define FT (F_*T_)
#define TB 64      // tokens per block (was 32) — 256B HBM granule per (c,d)
#define XS 136     // ushort stride of x tile rows

typedef __bf16 bf16x8 __attribute__((ext_vector_type(8)));
typedef float  floatx16 __attribute__((ext_vector_type(16)));

__device__ __forceinline__ u16 f2bf(float f) {
    union { __hip_bfloat16 h; u16 u; } cv; cv.h = __float2bfloat16(f); return cv.u;
}
__device__ __forceinline__ u32 pk2(float lo, float hi2) {
    union { __hip_bfloat162 h; u32 u; } cv;
    cv.h = __float22bfloat162_rn(make_float2(lo, hi2)); return cv.u;
}
__device__ __forceinline__ float bf2f(u16 u) { return __uint_as_float(((u32)u) << 16); }

// ---------------------------------------------------------------------------
// Precompute effective fused weights (unchanged).
// ---------------------------------------------------------------------------
__global__ __launch_bounds__(128) void precompute_eff(
    const float* __restrict__ lnqg, const float* __restrict__ lnqb,
    const float* __restrict__ lnkg, const float* __restrict__ lnkb,
    const float* __restrict__ Wq, const float* __restrict__ bq,
    const float* __restrict__ Wk, const float* __restrict__ bk,
    const float* __restrict__ Wv, const float* __restrict__ bv,
    const float* __restrict__ in_w, const float* __restrict__ in_b,
    const float* __restrict__ ow,
    u16* __restrict__ Agb, u16* __restrict__ Ob,
    float* __restrict__ sA, float* __restrict__ cb)
{
    const int j = blockIdx.x;
    const int sel = blockIdx.y;    // 0=q,1=k,2=v,3=out_w convert
    const int i = threadIdx.x;
    if (sel == 3) { Ob[j*D_ + i] = f2bf(ow[j*D_ + i]); return; }

    const float* W  = (sel==0) ? Wq : (sel==1) ? Wk : Wv;
    const float* bW = (sel==0) ? bq : (sel==1) ? bk : bv;
    const float* g  = (sel==0) ? lnqg : lnkg;
    const float* bl = (sel==0) ? lnqb : lnkb;

    __shared__ float row[D_];
    __shared__ float red[D_];
    row[i] = in_w[(sel*D_ + j)*D_ + i];
    __syncthreads();
    float acc = 0.f;
    #pragma unroll 8
    for (int m = 0; m < D_; ++m) acc = fmaf(row[m], W[m*D_ + i], acc);
    float ag = acc * g[i];
    Agb[sel*D_*D_ + j*D_ + i] = f2bf(ag);

    red[i] = ag;
    __syncthreads();
    for (int s = 64; s > 0; s >>= 1) { if (i < s) red[i] += red[i+s]; __syncthreads(); }
    if (i == 0) sA[sel*D_ + j] = red[0];
    __syncthreads();
    red[i] = acc * bl[i] + row[i] * bW[i];
    __syncthreads();
    for (int s = 64; s > 0; s >>= 1) { if (i < s) red[i] += red[i+s]; __syncthreads(); }
    if (i == 0) cb[sel*D_ + j] = red[0] + in_b[sel*D_ + j];
}

// ---------------------------------------------------------------------------
// Main fused kernel — Round 18 (2nd resubmit after infra timeouts): 64-token
// blocks (512 thr, 8 waves = 2 token-halves x 4 heads) to DOUBLE the HBM
// access granule.
//
// r17 post-mortem: time == traffic/1.05 TB/s across three structurally
// different kernels (r1/r2/r17) with all pipes <15% busy -> DRAM-pattern
// bound: (C,B,D,F,T) layout gives 128B islands at 256KB stride (no row
// locality). 64-token blocks make every h-read and out-write a 256B
// contiguous segment. Per-wave algorithm identical to r17 (verified):
// swapped-MFMA, in-register scores/softmax, factored folds.
// ---------------------------------------------------------------------------
__global__ __launch_bounds__(512, 4) void cca_mfma(
    const float* __restrict__ h,      // (C,B,128,F,T) fp32
    const u16*  __restrict__ Agb,     // 3 x [128][128] bf16 (q,k,v fused)
    const u16*  __restrict__ Ob,      // [128][128] bf16 out_w
    const float* __restrict__ sA,     // 3x128
    const float* __restrict__ cbp,    // 3x128
    const float* __restrict__ out_b,  // 128
    float* __restrict__ outp)         // (B,128,F,T)
{
    __shared__ __align__(16) u16 xb[4][TB*XS];    // 69632 B, r-scaled bf16 x
    __shared__ float rmneg[4][TB];                // 1024 B  -r*m per (c,t)
    __shared__ float invr[TB];                    // 256 B   1/r for c=0

    const int tid = threadIdx.x;
    const int blk = blockIdx.x;                  // 2048 = 2*256*4
    const int t0 = (blk & 3) * TB;
    const int f  = (blk >> 2) & 255;
    const int b  = blk >> 10;

    // ------- load all 4 context tiles (fp32 -> bf16 packed), 256B/row ------
    {
        const int dd = tid >> 4;          // d-pair index 0..31
        const int t4 = (tid & 15) * 4;    // token quad 0..60
        #pragma unroll
        for (int it = 0; it < 2; ++it) {
            const int d = 2*dd + 64*it;
            #pragma unroll
            for (int c = 0; c < 4; ++c) {
                const float* p = h + ((size_t)((c*B_ + b)*D_ + d))*FT + (size_t)f*T_ + t0 + t4;
                float4 v0 = *(const float4*)p;
                float4 v1 = *(const float4*)(p + FT);
                u32* dst = (u32*)xb[c] + dd + 32*it;
                dst[(size_t)(t4+0)*(XS/2)] = pk2(v0.x, v1.x);
                dst[(size_t)(t4+1)*(XS/2)] = pk2(v0.y, v1.y);
                dst[(size_t)(t4+2)*(XS/2)] = pk2(v0.z, v1.z);
                dst[(size_t)(t4+3)*(XS/2)] = pk2(v0.w, v1.w);
            }
        }
    }
    __syncthreads();

    // ---------- stats + in-place r-scale (thread = half-row of (c,t)) ------
    // 512 threads = 256 rows (4c x 64t) x 2 halves
    {
        const int rowi = tid >> 1, half = tid & 1;
        const int c = rowi >> 6, t = rowi & 63;
        u32* rowp = (u32*)(xb[c] + t*XS) + half*32;
        u32 rw[32];
        #pragma unroll
        for (int i = 0; i < 8; ++i) {
            uint4 q = ((const uint4*)rowp)[i];
            rw[4*i] = q.x; rw[4*i+1] = q.y; rw[4*i+2] = q.z; rw[4*i+3] = q.w;
        }
        float s = 0.f, sq = 0.f;
        #pragma unroll
        for (int k = 0; k < 32; ++k) {
            float lo = __uint_as_float(rw[k] << 16);
            float hi2 = __uint_as_float(rw[k] & 0xffff0000u);
            s += lo + hi2;
            sq = fmaf(lo, lo, fmaf(hi2, hi2, sq));
        }
        s += __shfl_xor(s, 1);
        sq += __shfl_xor(sq, 1);
        float m = s * (1.f/128.f);
        float var = fmaf(-m, m, sq * (1.f/128.f));
        float r = rsqrtf(var + 1e-5f);
        #pragma unroll
        for (int i = 0; i < 8; ++i) {
            uint4 q;
            q.x = pk2(__uint_as_float(rw[4*i]   << 16)*r, __uint_as_float(rw[4*i]   & 0xffff0000u)*r);
            q.y = pk2(__uint_as_float(rw[4*i+1] << 16)*r, __uint_as_float(rw[4*i+1] & 0xffff0000u)*r);
            q.z = pk2(__uint_as_float(rw[4*i+2] << 16)*r, __uint_as_float(rw[4*i+2] & 0xffff0000u)*r);
            q.w = pk2(__uint_as_float(rw[4*i+3] << 16)*r, __uint_as_float(rw[4*i+3] & 0xffff0000u)*r);
            ((uint4*)rowp)[i] = q;
        }
        if (half == 0) {
            rmneg[c][t] = -r*m;
            if (c == 0) invr[t] = 1.0f / r;
        }
    }
    __syncthreads();

    // -------- per-wave setup: wave = (token-half tp, head) -----------------
    const int wvall = tid >> 6;          // 0..7
    const int head  = wvall & 3;
    const int tp    = wvall >> 2;        // 0 or 1: token sub-tile
    const int l   = tid & 63;
    const int lo5 = l & 31, hi = l >> 5;
    const int jq   = head*32 + lo5;      // output dim owned by this lane pair
    const int tloc = tp*32 + lo5;        // token within block
    const int xoff = tloc*XS + hi*8;

    const u16* Bq = Agb +         (size_t)jq*D_ + hi*8;
    const u16* Bk = Agb + 16384 + (size_t)jq*D_ + hi*8;
    const u16* Bv = Agb + 32768 + (size_t)jq*D_ + hi*8;
    const u16* Bo = Ob  +         (size_t)jq*D_ + hi*8;

    // ---------------- q gemm (swapped): lane holds Q[token tloc][16 dims] --
    floatx16 qa;
    #pragma unroll
    for (int i = 0; i < 16; ++i) qa[i] = 0.f;
    __builtin_amdgcn_s_setprio(1);
    #pragma unroll
    for (int ks = 0; ks < 8; ++ks) {
        bf16x8 w = *(const bf16x8*)(Bq + ks*16);
        bf16x8 a = *(const bf16x8*)(xb[0] + xoff + ks*16);
        qa = __builtin_amdgcn_mfma_f32_32x32x16_bf16(w, a, qa, 0, 0, 0);
    }
    __builtin_amdgcn_s_setprio(0);
    // q fold: load, use, die (no long-lived vectors)
    {
        const float rm = rmneg[0][tloc];
        #pragma unroll
        for (int g = 0; g < 4; ++g) {
            float4 sv = *(const float4*)(sA  + head*32 + 8*g + 4*hi);
            float4 cv = *(const float4*)(cbp + head*32 + 8*g + 4*hi);
            qa[4*g+0] += fmaf(rm, sv.x, cv.x);
            qa[4*g+1] += fmaf(rm, sv.y, cv.y);
            qa[4*g+2] += fmaf(rm, sv.z, cv.z);
            qa[4*g+3] += fmaf(rm, sv.w, cv.w);
        }
    }

    // ---- k-correction dots: dqs = qa.sAk, dqc = qa.cbk (computed once) ----
    float dqs = 0.f, dqc = 0.f;
    #pragma unroll
    for (int g = 0; g < 4; ++g) {
        float4 sv = *(const float4*)(sA  + 128 + head*32 + 8*g + 4*hi);
        float4 cv = *(const float4*)(cbp + 128 + head*32 + 8*g + 4*hi);
        dqs = fmaf(qa[4*g+0], sv.x, dqs); dqc = fmaf(qa[4*g+0], cv.x, dqc);
        dqs = fmaf(qa[4*g+1], sv.y, dqs); dqc = fmaf(qa[4*g+1], cv.y, dqc);
        dqs = fmaf(qa[4*g+2], sv.z, dqs); dqc = fmaf(qa[4*g+2], cv.z, dqc);
        dqs = fmaf(qa[4*g+3], sv.w, dqs); dqc = fmaf(qa[4*g+3], cv.w, dqc);
    }

    // ---------------- k phase: 2x2 accs, in-register score dot -------------
    float sreg[4];
    #pragma unroll
    for (int cp = 0; cp < 4; cp += 2) {
        floatx16 k0, k1;
        #pragma unroll
        for (int i = 0; i < 16; ++i) { k0[i]=0.f; k1[i]=0.f; }
        __builtin_amdgcn_s_setprio(1);
        #pragma unroll
        for (int ks = 0; ks < 8; ++ks) {
            bf16x8 w  = *(const bf16x8*)(Bk + ks*16);
            bf16x8 a0 = *(const bf16x8*)(xb[cp]   + xoff + ks*16);
            bf16x8 a1 = *(const bf16x8*)(xb[cp+1] + xoff + ks*16);
            k0 = __builtin_amdgcn_mfma_f32_32x32x16_bf16(w, a0, k0, 0, 0, 0);
            k1 = __builtin_amdgcn_mfma_f32_32x32x16_bf16(w, a1, k1, 0, 0, 0);
        }
        __builtin_amdgcn_s_setprio(0);
        const float rm0 = rmneg[cp][tloc], rm1 = rmneg[cp+1][tloc];
        float p0 = fmaf(rm0, dqs, dqc);
        float p1 = fmaf(rm1, dqs, dqc);
        #pragma unroll
        for (int i = 0; i < 16; ++i) {
            p0 = fmaf(qa[i], k0[i], p0);
            p1 = fmaf(qa[i], k1[i], p1);
        }
        p0 += __shfl_xor(p0, 32);
        p1 += __shfl_xor(p1, 32);
        sreg[cp]   = p0 * 0.17677669529663687f;   // 1/sqrt(32)
        sreg[cp+1] = p1 * 0.17677669529663687f;
    }

    // ---------------- softmax fully in-register (all lanes) ----------------
    float w0, w1, w2, w3;
    {
        float mm = fmaxf(fmaxf(sreg[0], sreg[1]), fmaxf(sreg[2], sreg[3]));
        float e0 = __expf(sreg[0]-mm), e1 = __expf(sreg[1]-mm);
        float e2 = __expf(sreg[2]-mm), e3 = __expf(sreg[3]-mm);
        float inv = 1.f / (e0+e1+e2+e3);
        w0 = e0*inv; w1 = e1*inv; w2 = e2*inv; w3 = e3*inv;
    }

    // ---------------- v phase: 2x2 accs, scalar-weighted into ctx ----------
    floatx16 ctx;
    #pragma unroll
    for (int i = 0; i < 16; ++i) ctx[i] = 0.f;
    #pragma unroll
    for (int cp = 0; cp < 4; cp += 2) {
        floatx16 va0, va1;
        #pragma unroll
        for (int i = 0; i < 16; ++i) { va0[i]=0.f; va1[i]=0.f; }
        __builtin_amdgcn_s_setprio(1);
        #pragma unroll
        for (int ks = 0; ks < 8; ++ks) {
            bf16x8 w  = *(const bf16x8*)(Bv + ks*16);
            bf16x8 a0 = *(const bf16x8*)(xb[cp]   + xoff + ks*16);
            bf16x8 a1 = *(const bf16x8*)(xb[cp+1] + xoff + ks*16);
            va0 = __builtin_amdgcn_mfma_f32_32x32x16_bf16(w, a0, va0, 0, 0, 0);
            va1 = __builtin_amdgcn_mfma_f32_32x32x16_bf16(w, a1, va1, 0, 0, 0);
        }
        __builtin_amdgcn_s_setprio(0);
        const float wa = (cp==0) ? w0 : w2;
        const float wb = (cp==0) ? w1 : w3;
        #pragma unroll
        for (int i = 0; i < 16; ++i)
            ctx[i] = fmaf(wa, va0[i], fmaf(wb, va1[i], ctx[i]));
    }
    // v fold applied ONCE (sum_c w_c == 1): ctx += (sum w_c*rm_c)*sAv + cbv
    {
        float wr = w0*rmneg[0][tloc] + w1*rmneg[1][tloc]
                 + w2*rmneg[2][tloc] + w3*rmneg[3][tloc];
        #pragma unroll
        for (int g = 0; g < 4; ++g) {
            float4 sv = *(const float4*)(sA  + 256 + head*32 + 8*g + 4*hi);
            float4 cv = *(const float4*)(cbp + 256 + head*32 + 8*g + 4*hi);
            ctx[4*g+0] += fmaf(wr, sv.x, cv.x);
            ctx[4*g+1] += fmaf(wr, sv.y, cv.y);
            ctx[4*g+2] += fmaf(wr, sv.z, cv.z);
            ctx[4*g+3] += fmaf(wr, sv.w, cv.w);
        }
    }

    // ---------------- ctx -> xb[1] (bf16), out-proj, residual, store -------
    __syncthreads();                       // all waves done reading x tiles
    #pragma unroll
    for (int g = 0; g < 4; ++g) {
        // dims j = head*32 + 8g + 4hi + {0..3} for token tloc
        uint2 wr2;
        wr2.x = pk2(ctx[4*g+0], ctx[4*g+1]);
        wr2.y = pk2(ctx[4*g+2], ctx[4*g+3]);
        *(uint2*)(xb[1] + tloc*XS + head*32 + 8*g + 4*hi) = wr2;
    }
    __syncthreads();                       // ctx visible to all waves

    floatx16 oa;
    #pragma unroll
    for (int i = 0; i < 16; ++i) oa[i] = 0.f;
    __builtin_amdgcn_s_setprio(1);
    #pragma unroll
    for (int ks = 0; ks < 8; ++ks) {
        bf16x8 a  = *(const bf16x8*)(xb[1] + xoff + ks*16);
        bf16x8 bb = *(const bf16x8*)(Bo + ks*16);
        oa = __builtin_amdgcn_mfma_f32_32x32x16_bf16(a, bb, oa, 0, 0, 0);
    }
    __builtin_amdgcn_s_setprio(0);
    const float obv = out_b[jq];
    float* obase = outp + ((size_t)(b*D_ + jq))*FT + (size_t)f*T_ + t0 + tp*32;
    #pragma unroll
    for (int g = 0; g < 4; ++g) {
        const int tb = 8*g + 4*hi;           // token within this wave's 32
        const int tr = tp*32 + tb;           // token row in xb / invr
        float4 iv4 = *(const float4*)&invr[tr];
        float4 st;
        st.x = oa[g*4+0] + obv + bf2f(xb[0][(tr+0)*XS + jq]) * iv4.x;
        st.y = oa[g*4+1] + obv + bf2f(xb[0][(tr+1)*XS + jq]) * iv4.y;
        st.z = oa[g*4+2] + obv + bf2f(xb[0][(tr+2)*XS + jq]) * iv4.z;
        st.w = oa[g*4+3] + obv + bf2f(xb[0][(tr+3)*XS + jq]) * iv4.w;
        *(float4*)(obase + tb) = st;
    }
}

extern "C" void kernel_launch(void* const* d_in, const int* in_sizes, int n_in,
                              void* d_out, int out_size, void* d_ws, size_t ws_size,
                              hipStream_t stream) {
    const float* h    = (const float*)d_in[0];
    const float* lnqg = (const float*)d_in[1];
    const float* lnqb = (const float*)d_in[2];
    const float* lnkg = (const float*)d_in[3];
    const float* lnkb = (const float*)d_in[4];
    const float* Wq   = (const float*)d_in[5];
    const float* bq   = (const float*)d_in[6];
    const float* Wk   = (const float*)d_in[7];
    const float* bk   = (const float*)d_in[8];
    const float* Wv   = (const float*)d_in[9];
    const float* bv   = (const float*)d_in[10];
    const float* in_w = (const float*)d_in[11];
    const float* in_b = (const float*)d_in[12];
    const float* ow   = (const float*)d_in[13];
    const float* ob   = (const float*)d_in[14];

    char* ws = (char*)d_ws;
    u16*   Agb = (u16*)ws;                          // 3*16384 u16 = 98304 B
    u16*   Obf = (u16*)(ws + 98304);                // 16384 u16  = 32768 B
    float* sAe = (float*)(ws + 98304 + 32768);      // 384 f
    float* cbe = (float*)(ws + 98304 + 32768 + 1536);

    precompute_eff<<<dim3(128, 4), 128, 0, stream>>>(
        lnqg, lnqb, lnkg, lnkb, Wq, bq, Wk, bk, Wv, bv,
        in_w, in_b, ow, Agb, Obf, sAe, cbe);
    cca_mfma<<<dim3(B_*F_*(T_/TB)), 512, 0, stream>>>(
        h, Agb, Obf, sAe, cbe, ob, (float*)d_out);
}